// Round 5
// baseline (261.182 us; speedup 1.0000x reference)
//
#include <hip/hip_runtime.h>

// ---------------------------------------------------------------------------
// Discriminator fused pipeline for MI355X (gfx950) — all-MFMA main kernel.
//
//   h1[b, i*64+r, o] = relu( A1'[b*64+r, o] + sum_{t<8} W1br[o][t]*x_bi[r*8+t] )
//     A1' = input_flat @ W1a^T + b1 (prep, fp32; stored in MFMA C-frag layout),
//     W1br[o][t] = sum_{u<64} gmlp1_w[o][512+t*64+u]  (prep, bf16, K=32 zero-pad)
//   phase 1 = one 16x16x32 MFMA pass (K=8 effective), B-frags via ds_bpermute.
//   layers 2,3: transposed MFMA GEMMs D[o][m]; weights A-operand streamed from
//   L2 in pre-swizzled lane-contiguous layout (1 KB/wave/load, ping-pong
//   prefetch, no reg copies); activations B-operand in XOR-swizzled 64 KB LDS:
//     elem (row r, col c) at r*512 + (((c>>3) ^ (r&7))<<3) + (c&7)
//   Weight swizzle: elem (o,k) at (o>>4)*(8*K) + (k>>5)*512 + (((k>>3)&3)*16+(o&15))*8 + (k&7)
// ---------------------------------------------------------------------------

typedef float f32x4 __attribute__((ext_vector_type(4)));
typedef __bf16 bf16x8v __attribute__((ext_vector_type(8)));
typedef __bf16 bf16x4v __attribute__((ext_vector_type(4)));

// workspace byte offsets
#define WS_A1Q     0u           // 16 x 128 x 64 float4 = 2 MB  (A1+b1, C-frag layout)
#define WS_W1P     2097152u     // 512 x 32 bf16 = 32 KB (W1br zero-padded, A-swizzle)
#define WS_SENT    2129920u     // 16*512 f32 = 32 KB
#define WS_Y       2162688u     // 16*512 f32 = 32 KB (im-linear y)
#define WS_IMGEMB  2195456u     // 16*512 f32 = 32 KB
#define WS_W2BF    2228224u     // 512*512 bf16 = 512 KB (swizzled)
#define WS_W3BF    2752512u     // 512*512 bf16 = 512 KB (swizzled)
// total ~3.11 MB

// ---------------------------------------------------------------------------
// Prep: A1Q GEMM (blocks 0..127), W2/W3 swizzled bf16 convert (128..383),
// W1P + sent-zero (384..399), im-linear y (400..911)
// ---------------------------------------------------------------------------
__global__ __launch_bounds__(256) void k_prep(
    const float* __restrict__ input, const float* __restrict__ im_input,
    const float* __restrict__ g1w, const float* __restrict__ g1b,
    const float* __restrict__ g2w, const float* __restrict__ g3w,
    const float* __restrict__ imw, const float* __restrict__ imb,
    float* __restrict__ ws)
{
  __shared__ float As[16][72];
  __shared__ float Bs[16][72];
  const int blk = blockIdx.x, t = threadIdx.x;
  float4* A1Q = (float4*)ws;
  __bf16* w1p = (__bf16*)((char*)ws + WS_W1P);
  float* sent = (float*)((char*)ws + WS_SENT);
  float* yv   = (float*)((char*)ws + WS_Y);
  __bf16* w2bf = (__bf16*)((char*)ws + WS_W2BF);
  __bf16* w3bf = (__bf16*)((char*)ws + WS_W3BF);

  if (blk < 128) {
    // A1[1024,512] = input_flat @ W1a^T + b1 ; W1a = gmlp1_w[:, :512]
    const int tm = blk >> 3, tn = blk & 7;     // tm = b, tn = o-tile
    const int m0 = tm * 64, o0 = tn * 64;
    const int ty = t >> 4, tx = t & 15;
    const int lrow = t >> 2, lk4 = (t & 3) * 4;
    float acc[4][4] = {};
    for (int kc = 0; kc < 512; kc += 16) {
      float4 av = *(const float4*)(input + (m0 + lrow) * 512 + kc + lk4);
      float4 bw = *(const float4*)(g1w + (size_t)(o0 + lrow) * 1024 + kc + lk4);
      __syncthreads();
      As[lk4 + 0][lrow] = av.x; As[lk4 + 1][lrow] = av.y;
      As[lk4 + 2][lrow] = av.z; As[lk4 + 3][lrow] = av.w;
      Bs[lk4 + 0][lrow] = bw.x; Bs[lk4 + 1][lrow] = bw.y;
      Bs[lk4 + 2][lrow] = bw.z; Bs[lk4 + 3][lrow] = bw.w;
      __syncthreads();
#pragma unroll
      for (int kk = 0; kk < 16; ++kk) {
        float a4[4], b4[4];
        *(float4*)a4 = *(const float4*)&As[kk][4 * ty];
        *(float4*)b4 = *(const float4*)&Bs[kk][4 * tx];
#pragma unroll
        for (int ii = 0; ii < 4; ++ii)
#pragma unroll
          for (int jj = 0; jj < 4; ++jj)
            acc[ii][jj] += a4[ii] * b4[jj];
      }
    }
    // write C-frag layout: A1Q[(b*128 + o4)*64 + m]; o4 = (o0>>2)+tx, m = 4ty+ii
    float4 bias = *(const float4*)(g1b + o0 + 4 * tx);
#pragma unroll
    for (int ii = 0; ii < 4; ++ii) {
      float4 v;
      v.x = acc[ii][0] + bias.x; v.y = acc[ii][1] + bias.y;
      v.z = acc[ii][2] + bias.z; v.w = acc[ii][3] + bias.w;
      A1Q[(tm * 128 + tn * 16 + tx) * 64 + 4 * ty + ii] = v;
    }
  } else if (blk < 384) {
    // convert gmlp2_w / gmlp3_w to bf16 in MFMA A-frag swizzled layout (K=512)
    int idx = ((blk - 128) * 256 + t) * 8;
    const float* src; __bf16* dst; int off;
    if (idx < 262144) { src = g2w; dst = w2bf; off = idx; }
    else              { src = g3w; dst = w3bf; off = idx - 262144; }
    int o = off >> 9, k = off & 511;
    int ks = k >> 5, quad = (k >> 3) & 3;
    int doff = (o >> 4) * 8192 + ks * 512 + (quad * 16 + (o & 15)) * 8;
    float4 v0 = *(const float4*)(src + off);
    float4 v1 = *(const float4*)(src + off + 4);
    bf16x8v h;
    h[0] = (__bf16)v0.x; h[1] = (__bf16)v0.y; h[2] = (__bf16)v0.z; h[3] = (__bf16)v0.w;
    h[4] = (__bf16)v1.x; h[5] = (__bf16)v1.y; h[6] = (__bf16)v1.z; h[7] = (__bf16)v1.w;
    *(bf16x8v*)(dst + doff) = h;
  } else if (blk < 400) {
    // W1P[o][s] = sum_{u<64} gmlp1_w[o][512 + s*64 + u], bf16, A-swizzle, K=32 pad
    int idx = (blk - 384) * 256 + t;      // 0..4095
    int o = idx >> 3, s = idx & 7;
    const float* p = g1w + (size_t)o * 1024 + 512 + s * 64;
    float sum = 0.f;
#pragma unroll
    for (int u = 0; u < 64; u += 4) {
      float4 v = *(const float4*)(p + u);
      sum += v.x + v.y + v.z + v.w;
    }
    int base = (o >> 4) * 512 + (o & 15) * 8 + s;   // quad 0 slot
    w1p[base]       = (__bf16)sum;
    w1p[base + 128] = (__bf16)0.f;                  // quads 1..3 = zero pad
    w1p[base + 256] = (__bf16)0.f;
    w1p[base + 384] = (__bf16)0.f;
    sent[idx] = 0.f; sent[idx + 4096] = 0.f;        // zero accumulator
  } else {
    // y[b][o] = dot(im_input[b], im_w[o]) + im_b[o]; one block per o
    int o = blk - 400;                    // 0..511
    int wv = t >> 6, l = t & 63;
    const float* wrow = imw + (size_t)o * 2048;
    for (int bb = 0; bb < 4; ++bb) {
      int b = wv * 4 + bb;
      const float* xr = im_input + (size_t)b * 2048;
      float s = 0.f;
#pragma unroll
      for (int u = 0; u < 8; ++u) {
        int k = u * 256 + l * 4;
        float4 xv = *(const float4*)(xr + k);
        float4 wx = *(const float4*)(wrow + k);
        s += xv.x * wx.x + xv.y * wx.y + xv.z * wx.z + xv.w * wx.w;
      }
#pragma unroll
      for (int m = 32; m >= 1; m >>= 1) s += __shfl_xor(s, m);
      if (l == 0) yv[b * 512 + o] = s + imb[o];
    }
  }
}

// ---------------------------------------------------------------------------
// Transposed-GEMM K-loop, ping-pong A-prefetch (no register copies).
// ---------------------------------------------------------------------------
__device__ __forceinline__ void kloop(const __bf16* __restrict__ wl,
                                      const __bf16* __restrict__ hbuf,
                                      int p16, int quad, f32x4 acc[8][4])
{
  const int msk3 = (p16 & 7) << 3;
  bf16x8v areg[2][8];
#pragma unroll
  for (int ot = 0; ot < 8; ++ot) areg[0][ot] = *(const bf16x8v*)(wl + ot * 8192);
#pragma unroll
  for (int ks = 0; ks < 16; ++ks) {
    const int cur = ks & 1, nxt = cur ^ 1;
    if (ks < 15) {
#pragma unroll
      for (int ot = 0; ot < 8; ++ot)
        areg[nxt][ot] = *(const bf16x8v*)(wl + (ks + 1) * 512 + ot * 8192);
    }
    const int kcb = (((ks * 4 + quad) << 3) ^ msk3);
    bf16x8v bf[4];
#pragma unroll
    for (int mt = 0; mt < 4; ++mt)
      bf[mt] = *(const bf16x8v*)(hbuf + (p16 + 16 * mt) * 512 + kcb);
#pragma unroll
    for (int ot = 0; ot < 8; ++ot)
#pragma unroll
      for (int mt = 0; mt < 4; ++mt)
        acc[ot][mt] = __builtin_amdgcn_mfma_f32_16x16x32_bf16(areg[cur][ot], bf[mt], acc[ot][mt], 0, 0, 0);
  }
}

// ---------------------------------------------------------------------------
// Main fused kernel: blocks 0..1023 = (b,i) pair tiles; block 1024 = BatchNorm
// ---------------------------------------------------------------------------
__global__ __launch_bounds__(256, 2) void k_main(
    const float* __restrict__ input,
    const float* __restrict__ g2b, const float* __restrict__ g3b,
    const float* __restrict__ bng, const float* __restrict__ bnb,
    float* __restrict__ ws)
{
  const int blk = blockIdx.x, t = threadIdx.x;
  const float4* A1Q = (const float4*)ws;
  const __bf16* w1p = (const __bf16*)((char*)ws + WS_W1P);
  float* sent = (float*)((char*)ws + WS_SENT);
  float* yv   = (float*)((char*)ws + WS_Y);
  float* imge = (float*)((char*)ws + WS_IMGEMB);
  const __bf16* w2bf = (const __bf16*)((char*)ws + WS_W2BF);
  const __bf16* w3bf = (const __bf16*)((char*)ws + WS_W3BF);

  if (blk == 1024) {
    // BatchNorm1d (training-mode batch stats) + ReLU over y[16][512]
#pragma unroll
    for (int rep = 0; rep < 2; ++rep) {
      int o = t + rep * 256;
      float vals[16];
      float mu = 0.f;
#pragma unroll
      for (int b = 0; b < 16; ++b) { vals[b] = yv[b * 512 + o]; mu += vals[b]; }
      mu *= (1.f / 16.f);
      float var = 0.f;
#pragma unroll
      for (int b = 0; b < 16; ++b) { float d = vals[b] - mu; var += d * d; }
      var *= (1.f / 16.f);
      float sc = bng[o] * rsqrtf(var + 1e-5f);
      float sh = bnb[o] - mu * sc;
#pragma unroll
      for (int b = 0; b < 16; ++b)
        imge[b * 512 + o] = fmaxf(vals[b] * sc + sh, 0.f);
    }
    return;
  }

  __shared__ __align__(16) __bf16 hbuf[32768];   // 64 x 512, swizzled; 64 KB

  const int b = blk >> 6, i = blk & 63;
  const int w = t >> 6, l = t & 63;
  const int quad = l >> 4, p16 = l & 15;

  // x row (input[b,i,:]): lane l holds x[l*8 .. l*8+7]
  float xreg[8];
  {
    const float* xr = input + (size_t)(b * 64 + i) * 512 + l * 8;
    *(float4*)xreg       = *(const float4*)xr;
    *(float4*)(xreg + 4) = *(const float4*)(xr + 4);
  }

  f32x4 acc[8][4];

  // ---- phase 1: h1 = relu(A1' + W1br @ x) via one K=32 MFMA pass ----
  {
    // B-frags via bpermute: lane needs x[(p16+16mt)*8 + j] on quad 0, else 0
    bf16x8v xb[4];
#pragma unroll
    for (int mt = 0; mt < 4; ++mt) {
#pragma unroll
      for (int j = 0; j < 8; ++j) {
        float v = __shfl(xreg[j], p16 + 16 * mt);
        xb[mt][j] = (quad == 0) ? (__bf16)v : (__bf16)0.f;
      }
    }
#pragma unroll
    for (int ot = 0; ot < 8; ++ot)
#pragma unroll
      for (int mt = 0; mt < 4; ++mt) { f32x4 z = {0.f, 0.f, 0.f, 0.f}; acc[ot][mt] = z; }
#pragma unroll
    for (int ot = 0; ot < 8; ++ot) {
      bf16x8v af = *(const bf16x8v*)(w1p + (w * 8 + ot) * 512 + l * 8);
#pragma unroll
      for (int mt = 0; mt < 4; ++mt)
        acc[ot][mt] = __builtin_amdgcn_mfma_f32_16x16x32_bf16(af, xb[mt], acc[ot][mt], 0, 0, 0);
    }
    // C-add (A1' in C-frag layout) + relu + write swizzled LDS
    const float4* cq = A1Q + ((size_t)b * 128 + w * 32) * 64;
#pragma unroll
    for (int ot = 0; ot < 8; ++ot) {
#pragma unroll
      for (int mt = 0; mt < 4; ++mt) {
        float4 c = cq[(ot * 4 + quad) * 64 + 16 * mt + p16];
        f32x4 v = acc[ot][mt];
        bf16x4v h;
        h[0] = (__bf16)fmaxf(v[0] + c.x, 0.f);
        h[1] = (__bf16)fmaxf(v[1] + c.y, 0.f);
        h[2] = (__bf16)fmaxf(v[2] + c.z, 0.f);
        h[3] = (__bf16)fmaxf(v[3] + c.w, 0.f);
        int row = p16 + 16 * mt;
        int col = w * 128 + ot * 16 + quad * 4;
        *(bf16x4v*)(hbuf + row * 512 + (((col >> 3) ^ (row & 7)) << 3) + (col & 7)) = h;
      }
    }
  }
  __syncthreads();

  // ---- phase 2: h2 = relu(h1 @ W2^T + b2) ----
#pragma unroll
  for (int ot = 0; ot < 8; ++ot)
#pragma unroll
    for (int mt = 0; mt < 4; ++mt) { f32x4 z = {0.f, 0.f, 0.f, 0.f}; acc[ot][mt] = z; }

  kloop(w2bf + (size_t)(w * 8) * 8192 + l * 8, hbuf, p16, quad, acc);
  __syncthreads();  // all h1 reads done before overwrite
#pragma unroll
  for (int ot = 0; ot < 8; ++ot) {
    float4 b2 = *(const float4*)(g2b + w * 128 + ot * 16 + quad * 4);
#pragma unroll
    for (int mt = 0; mt < 4; ++mt) {
      f32x4 v = acc[ot][mt];
      bf16x4v h;
      h[0] = (__bf16)fmaxf(v[0] + b2.x, 0.f);
      h[1] = (__bf16)fmaxf(v[1] + b2.y, 0.f);
      h[2] = (__bf16)fmaxf(v[2] + b2.z, 0.f);
      h[3] = (__bf16)fmaxf(v[3] + b2.w, 0.f);
      int row = p16 + 16 * mt;
      int col = w * 128 + ot * 16 + quad * 4;
      *(bf16x4v*)(hbuf + row * 512 + (((col >> 3) ^ (row & 7)) << 3) + (col & 7)) = h;
    }
  }
  __syncthreads();

  // ---- phase 3: h3 = relu(h2 @ W3^T + b3), fused mean-reduce ----
#pragma unroll
  for (int ot = 0; ot < 8; ++ot)
#pragma unroll
    for (int mt = 0; mt < 4; ++mt) { f32x4 z = {0.f, 0.f, 0.f, 0.f}; acc[ot][mt] = z; }

  kloop(w3bf + (size_t)(w * 8) * 8192 + l * 8, hbuf, p16, quad, acc);

#pragma unroll
  for (int ot = 0; ot < 8; ++ot) {
    float4 b3 = *(const float4*)(g3b + w * 128 + ot * 16 + quad * 4);
    float bb[4] = {b3.x, b3.y, b3.z, b3.w};
#pragma unroll
    for (int r = 0; r < 4; ++r) {
      float s = 0.f;
#pragma unroll
      for (int mt = 0; mt < 4; ++mt) s += fmaxf(acc[ot][mt][r] + bb[r], 0.f);
      s += __shfl_xor(s, 1);
      s += __shfl_xor(s, 2);
      s += __shfl_xor(s, 4);
      s += __shfl_xor(s, 8);
      if (p16 == 0)
        atomicAdd(&sent[b * 512 + w * 128 + ot * 16 + quad * 4 + r], s * (1.0f / 4096.0f));
    }
  }
}

// ---------------------------------------------------------------------------
// Head (fused): 64 blocks = 16 b x 4 row-slices of 128, 128 threads (2 waves).
// Wave-cooperative rows: coalesced 1 KB/instr d1w reads, butterfly reduce,
// then p0/p1 partials atomically added into (pre-zeroed) out.
// ---------------------------------------------------------------------------
__global__ __launch_bounds__(128) void k_head(
    const float* __restrict__ d1w, const float* __restrict__ d1b,
    const float* __restrict__ d2w, const float* __restrict__ d2b,
    const float* __restrict__ ws, float* __restrict__ out)
{
  __shared__ float emb[1024];
  const float* sent = (const float*)((const char*)ws + WS_SENT);
  const float* imge = (const float*)((const char*)ws + WS_IMGEMB);
  const int b = blockIdx.x >> 2, sl = blockIdx.x & 3, t = threadIdx.x;
  ((float4*)emb)[t]       = ((const float4*)(sent + b * 512))[t];
  ((float4*)(emb + 512))[t] = ((const float4*)(imge + b * 512))[t];
  __syncthreads();
  const int w2 = t >> 6, l = t & 63;
  float p0 = 0.f, p1 = 0.f;
  for (int rr = 0; rr < 64; ++rr) {
    int row = sl * 128 + w2 * 64 + rr;
    const float* wr = d1w + (size_t)row * 1024 + l * 4;
    float s = 0.f;
#pragma unroll
    for (int c = 0; c < 4; ++c) {
      float4 wv = *(const float4*)(wr + c * 256);
      float4 ev = *(const float4*)(emb + l * 4 + c * 256);
      s += wv.x * ev.x + wv.y * ev.y + wv.z * ev.z + wv.w * ev.w;
    }
#pragma unroll
    for (int m = 32; m >= 1; m >>= 1) s += __shfl_xor(s, m);
    float h = fmaxf(s + d1b[row], 0.f);
    p0 += d2w[row] * h;
    p1 += d2w[512 + row] * h;
  }
  if (l == 0) {
    if (sl == 0 && w2 == 0) { p0 += d2b[0]; p1 += d2b[1]; }
    atomicAdd(&out[b * 2 + 0], p0);
    atomicAdd(&out[b * 2 + 1], p1);
  }
}

// ---------------------------------------------------------------------------
extern "C" void kernel_launch(void* const* d_in, const int* in_sizes, int n_in,
                              void* d_out, int out_size, void* d_ws, size_t ws_size,
                              hipStream_t stream)
{
  const float* input    = (const float*)d_in[0];
  const float* im_input = (const float*)d_in[1];
  const float* g1w = (const float*)d_in[2];
  const float* g1b = (const float*)d_in[3];
  const float* g2w = (const float*)d_in[4];
  const float* g2b = (const float*)d_in[5];
  const float* g3w = (const float*)d_in[6];
  const float* g3b = (const float*)d_in[7];
  const float* imw = (const float*)d_in[8];
  const float* imb = (const float*)d_in[9];
  const float* bng = (const float*)d_in[10];
  const float* bnb = (const float*)d_in[11];
  const float* d1w = (const float*)d_in[12];
  const float* d1b = (const float*)d_in[13];
  const float* d2w = (const float*)d_in[14];
  const float* d2b = (const float*)d_in[15];
  float* out = (float*)d_out;
  float* ws  = (float*)d_ws;

  hipMemsetAsync(d_out, 0, (size_t)out_size * 4, stream);
  k_prep<<<912, 256, 0, stream>>>(input, im_input, g1w, g1b, g2w, g3w, imw, imb, ws);
  k_main<<<1025, 256, 0, stream>>>(input, g2b, g3b, bng, bnb, ws);
  k_head<<<64, 128, 0, stream>>>(d1w, d1b, d2w, d2b, ws, out);
}

// Round 6
// 217.415 us; speedup vs baseline: 1.2013x; 1.2013x over previous
//
#include <hip/hip_runtime.h>

// ---------------------------------------------------------------------------
// Discriminator fused pipeline for MI355X (gfx950) — all-MFMA main kernel.
//
//   h1[b, i*64+r, o] = relu( A1'[b*64+r, o] + sum_{t<8} W1br[o][t]*x_bi[r*8+t] )
//     A1' = input_flat @ W1a^T + b1 (prep, fp32; stored in MFMA C-frag layout),
//     W1br[o][t] = sum_{u<64} gmlp1_w[o][512+t*64+u]  (prep, bf16, K=32 zero-pad)
//   phase 1 = one 16x16x32 MFMA pass (K=8 effective), B-frags via shfl bcast.
//   layers 2,3: transposed MFMA GEMMs D[o][m]; weights A-operand streamed from
//   L2 in pre-swizzled lane-contiguous layout (1 KB/wave/load), kloop uses the
//   ROUND-4 split prefetch schedule (measured best); activations B-operand in
//   XOR-swizzled 64 KB LDS: elem (r,c) at r*512 + (((c>>3) ^ (r&7))<<3) + (c&7)
//   Weight swizzle: elem (o,k) at (o>>4)*8192 + (k>>5)*512 + (((k>>3)&3)*16+(o&15))*8 + (k&7)
// ---------------------------------------------------------------------------

typedef float f32x4 __attribute__((ext_vector_type(4)));
typedef __bf16 bf16x8v __attribute__((ext_vector_type(8)));
typedef __bf16 bf16x4v __attribute__((ext_vector_type(4)));

// workspace byte offsets
#define WS_A1Q     0u           // 16 x 128 x 64 float4 = 2 MB  (A1+b1, C-frag layout)
#define WS_W1P     2097152u     // 512 x 32 bf16 = 32 KB (W1br zero-padded, A-swizzle)
#define WS_SENT    2129920u     // 16*512 f32 = 32 KB
#define WS_Y       2162688u     // 16*512 f32 = 32 KB (im-linear y)
#define WS_IMGEMB  2195456u     // 16*512 f32 = 32 KB
#define WS_W2BF    2228224u     // 512*512 bf16 = 512 KB (swizzled)
#define WS_W3BF    2752512u     // 512*512 bf16 = 512 KB (swizzled)
// total ~3.11 MB

// ---------------------------------------------------------------------------
// Prep: A1Q GEMM (blocks 0..127), W2/W3 swizzled bf16 convert (128..383),
// W1P + sent-zero (384..399), im-linear y (400..911)
// ---------------------------------------------------------------------------
__global__ __launch_bounds__(256) void k_prep(
    const float* __restrict__ input, const float* __restrict__ im_input,
    const float* __restrict__ g1w, const float* __restrict__ g1b,
    const float* __restrict__ g2w, const float* __restrict__ g3w,
    const float* __restrict__ imw, const float* __restrict__ imb,
    float* __restrict__ ws)
{
  __shared__ float As[16][72];
  __shared__ float Bs[16][72];
  const int blk = blockIdx.x, t = threadIdx.x;
  float4* A1Q = (float4*)ws;
  __bf16* w1p = (__bf16*)((char*)ws + WS_W1P);
  float* sent = (float*)((char*)ws + WS_SENT);
  float* yv   = (float*)((char*)ws + WS_Y);
  __bf16* w2bf = (__bf16*)((char*)ws + WS_W2BF);
  __bf16* w3bf = (__bf16*)((char*)ws + WS_W3BF);

  if (blk < 128) {
    // A1[1024,512] = input_flat @ W1a^T + b1 ; W1a = gmlp1_w[:, :512]
    const int tm = blk >> 3, tn = blk & 7;     // tm = b, tn = o-tile
    const int m0 = tm * 64, o0 = tn * 64;
    const int ty = t >> 4, tx = t & 15;
    const int lrow = t >> 2, lk4 = (t & 3) * 4;
    float acc[4][4] = {};
    for (int kc = 0; kc < 512; kc += 16) {
      float4 av = *(const float4*)(input + (m0 + lrow) * 512 + kc + lk4);
      float4 bw = *(const float4*)(g1w + (size_t)(o0 + lrow) * 1024 + kc + lk4);
      __syncthreads();
      As[lk4 + 0][lrow] = av.x; As[lk4 + 1][lrow] = av.y;
      As[lk4 + 2][lrow] = av.z; As[lk4 + 3][lrow] = av.w;
      Bs[lk4 + 0][lrow] = bw.x; Bs[lk4 + 1][lrow] = bw.y;
      Bs[lk4 + 2][lrow] = bw.z; Bs[lk4 + 3][lrow] = bw.w;
      __syncthreads();
#pragma unroll
      for (int kk = 0; kk < 16; ++kk) {
        float a4[4], b4[4];
        *(float4*)a4 = *(const float4*)&As[kk][4 * ty];
        *(float4*)b4 = *(const float4*)&Bs[kk][4 * tx];
#pragma unroll
        for (int ii = 0; ii < 4; ++ii)
#pragma unroll
          for (int jj = 0; jj < 4; ++jj)
            acc[ii][jj] += a4[ii] * b4[jj];
      }
    }
    // write C-frag layout: A1Q[(b*128 + o4)*64 + m]; o4 = (o0>>2)+tx, m = 4ty+ii
    float4 bias = *(const float4*)(g1b + o0 + 4 * tx);
#pragma unroll
    for (int ii = 0; ii < 4; ++ii) {
      float4 v;
      v.x = acc[ii][0] + bias.x; v.y = acc[ii][1] + bias.y;
      v.z = acc[ii][2] + bias.z; v.w = acc[ii][3] + bias.w;
      A1Q[(tm * 128 + tn * 16 + tx) * 64 + 4 * ty + ii] = v;
    }
  } else if (blk < 384) {
    // convert gmlp2_w / gmlp3_w to bf16 in MFMA A-frag swizzled layout (K=512)
    int idx = ((blk - 128) * 256 + t) * 8;
    const float* src; __bf16* dst; int off;
    if (idx < 262144) { src = g2w; dst = w2bf; off = idx; }
    else              { src = g3w; dst = w3bf; off = idx - 262144; }
    int o = off >> 9, k = off & 511;
    int ks = k >> 5, quad = (k >> 3) & 3;
    int doff = (o >> 4) * 8192 + ks * 512 + (quad * 16 + (o & 15)) * 8;
    float4 v0 = *(const float4*)(src + off);
    float4 v1 = *(const float4*)(src + off + 4);
    bf16x8v h;
    h[0] = (__bf16)v0.x; h[1] = (__bf16)v0.y; h[2] = (__bf16)v0.z; h[3] = (__bf16)v0.w;
    h[4] = (__bf16)v1.x; h[5] = (__bf16)v1.y; h[6] = (__bf16)v1.z; h[7] = (__bf16)v1.w;
    *(bf16x8v*)(dst + doff) = h;
  } else if (blk < 400) {
    // W1P[o][s] = sum_{u<64} gmlp1_w[o][512 + s*64 + u], bf16, A-swizzle, K=32 pad
    int idx = (blk - 384) * 256 + t;      // 0..4095
    int o = idx >> 3, s = idx & 7;
    const float* p = g1w + (size_t)o * 1024 + 512 + s * 64;
    float sum = 0.f;
#pragma unroll
    for (int u = 0; u < 64; u += 4) {
      float4 v = *(const float4*)(p + u);
      sum += v.x + v.y + v.z + v.w;
    }
    int base = (o >> 4) * 512 + (o & 15) * 8 + s;   // quad 0 slot
    w1p[base]       = (__bf16)sum;
    w1p[base + 128] = (__bf16)0.f;                  // quads 1..3 = zero pad
    w1p[base + 256] = (__bf16)0.f;
    w1p[base + 384] = (__bf16)0.f;
    sent[idx] = 0.f; sent[idx + 4096] = 0.f;        // zero accumulator
  } else {
    // y[b][o] = dot(im_input[b], im_w[o]) + im_b[o]; one block per o
    int o = blk - 400;                    // 0..511
    int wv = t >> 6, l = t & 63;
    const float* wrow = imw + (size_t)o * 2048;
    for (int bb = 0; bb < 4; ++bb) {
      int b = wv * 4 + bb;
      const float* xr = im_input + (size_t)b * 2048;
      float s = 0.f;
#pragma unroll
      for (int u = 0; u < 8; ++u) {
        int k = u * 256 + l * 4;
        float4 xv = *(const float4*)(xr + k);
        float4 wx = *(const float4*)(wrow + k);
        s += xv.x * wx.x + xv.y * wx.y + xv.z * wx.z + xv.w * wx.w;
      }
#pragma unroll
      for (int m = 32; m >= 1; m >>= 1) s += __shfl_xor(s, m);
      if (l == 0) yv[b * 512 + o] = s + imb[o];
    }
  }
}

// ---------------------------------------------------------------------------
// Transposed-GEMM K-loop — ROUND-4 schedule (measured 106.6 µs): split 4+4
// A-frags, prefetch interleaved between MFMA halves, unroll 2.
// ---------------------------------------------------------------------------
__device__ __forceinline__ void kloop(const __bf16* __restrict__ wl,
                                      const __bf16* __restrict__ hbuf,
                                      int p16, int quad, f32x4 acc[8][4])
{
  const int msk3 = (p16 & 7) << 3;
  bf16x8v a0[4], a1[4], an[4];
#pragma unroll
  for (int ot = 0; ot < 4; ++ot) a0[ot] = *(const bf16x8v*)(wl + ot * 8192);
#pragma unroll
  for (int ot = 0; ot < 4; ++ot) a1[ot] = *(const bf16x8v*)(wl + (ot + 4) * 8192);
#pragma unroll 2
  for (int ks = 0; ks < 16; ++ks) {
    const int kcb = (((ks * 4 + quad) << 3) ^ msk3);
    bf16x8v bf[4];
#pragma unroll
    for (int mt = 0; mt < 4; ++mt)
      bf[mt] = *(const bf16x8v*)(hbuf + (p16 + 16 * mt) * 512 + kcb);
    if (ks < 15) {
#pragma unroll
      for (int ot = 0; ot < 4; ++ot)
        an[ot] = *(const bf16x8v*)(wl + (ks + 1) * 512 + ot * 8192);
    }
#pragma unroll
    for (int ot = 0; ot < 4; ++ot)
#pragma unroll
      for (int mt = 0; mt < 4; ++mt)
        acc[ot][mt] = __builtin_amdgcn_mfma_f32_16x16x32_bf16(a0[ot], bf[mt], acc[ot][mt], 0, 0, 0);
#pragma unroll
    for (int ot = 0; ot < 4; ++ot)
#pragma unroll
      for (int mt = 0; mt < 4; ++mt)
        acc[4 + ot][mt] = __builtin_amdgcn_mfma_f32_16x16x32_bf16(a1[ot], bf[mt], acc[4 + ot][mt], 0, 0, 0);
    if (ks < 15) {
#pragma unroll
      for (int ot = 0; ot < 4; ++ot)
        a1[ot] = *(const bf16x8v*)(wl + (ks + 1) * 512 + (ot + 4) * 8192);
#pragma unroll
      for (int ot = 0; ot < 4; ++ot) a0[ot] = an[ot];
    }
  }
}

// ---------------------------------------------------------------------------
// Main fused kernel: blocks 0..1023 = (b,i) pair tiles; block 1024 = BatchNorm
// ---------------------------------------------------------------------------
__global__ __launch_bounds__(256, 2) void k_main(
    const float* __restrict__ input,
    const float* __restrict__ g2b, const float* __restrict__ g3b,
    const float* __restrict__ bng, const float* __restrict__ bnb,
    float* __restrict__ ws)
{
  const int blk = blockIdx.x, t = threadIdx.x;
  const float4* A1Q = (const float4*)ws;
  const __bf16* w1p = (const __bf16*)((char*)ws + WS_W1P);
  float* sent = (float*)((char*)ws + WS_SENT);
  float* yv   = (float*)((char*)ws + WS_Y);
  float* imge = (float*)((char*)ws + WS_IMGEMB);
  const __bf16* w2bf = (const __bf16*)((char*)ws + WS_W2BF);
  const __bf16* w3bf = (const __bf16*)((char*)ws + WS_W3BF);

  if (blk == 1024) {
    // BatchNorm1d (training-mode batch stats) + ReLU over y[16][512]
#pragma unroll
    for (int rep = 0; rep < 2; ++rep) {
      int o = t + rep * 256;
      float vals[16];
      float mu = 0.f;
#pragma unroll
      for (int b = 0; b < 16; ++b) { vals[b] = yv[b * 512 + o]; mu += vals[b]; }
      mu *= (1.f / 16.f);
      float var = 0.f;
#pragma unroll
      for (int b = 0; b < 16; ++b) { float d = vals[b] - mu; var += d * d; }
      var *= (1.f / 16.f);
      float sc = bng[o] * rsqrtf(var + 1e-5f);
      float sh = bnb[o] - mu * sc;
#pragma unroll
      for (int b = 0; b < 16; ++b)
        imge[b * 512 + o] = fmaxf(vals[b] * sc + sh, 0.f);
    }
    return;
  }

  __shared__ __align__(16) __bf16 hbuf[32768];   // 64 x 512, swizzled; 64 KB

  const int b = blk >> 6, i = blk & 63;
  const int w = t >> 6, l = t & 63;
  const int quad = l >> 4, p16 = l & 15;

  // x row (input[b,i,:]): lane l holds x[l*8 .. l*8+7]
  float xreg[8];
  {
    const float* xr = input + (size_t)(b * 64 + i) * 512 + l * 8;
    *(float4*)xreg       = *(const float4*)xr;
    *(float4*)(xreg + 4) = *(const float4*)(xr + 4);
  }

  f32x4 acc[8][4];

  // ---- phase 1: h1 = relu(A1' + W1br @ x) via one K=32 MFMA pass ----
  {
    // B-frags: lane needs x[(p16+16mt)*8 + j] on quad 0, else 0
    bf16x8v xb[4];
#pragma unroll
    for (int mt = 0; mt < 4; ++mt) {
#pragma unroll
      for (int j = 0; j < 8; ++j) {
        float v = __shfl(xreg[j], p16 + 16 * mt);
        xb[mt][j] = (quad == 0) ? (__bf16)v : (__bf16)0.f;
      }
    }
#pragma unroll
    for (int ot = 0; ot < 8; ++ot)
#pragma unroll
      for (int mt = 0; mt < 4; ++mt) { f32x4 z = {0.f, 0.f, 0.f, 0.f}; acc[ot][mt] = z; }
#pragma unroll
    for (int ot = 0; ot < 8; ++ot) {
      bf16x8v af = *(const bf16x8v*)(w1p + (w * 8 + ot) * 512 + l * 8);
#pragma unroll
      for (int mt = 0; mt < 4; ++mt)
        acc[ot][mt] = __builtin_amdgcn_mfma_f32_16x16x32_bf16(af, xb[mt], acc[ot][mt], 0, 0, 0);
    }
    // C-add (A1' in C-frag layout) + relu + write swizzled LDS
    const float4* cq = A1Q + ((size_t)b * 128 + w * 32) * 64;
#pragma unroll
    for (int ot = 0; ot < 8; ++ot) {
#pragma unroll
      for (int mt = 0; mt < 4; ++mt) {
        float4 c = cq[(ot * 4 + quad) * 64 + 16 * mt + p16];
        f32x4 v = acc[ot][mt];
        bf16x4v h;
        h[0] = (__bf16)fmaxf(v[0] + c.x, 0.f);
        h[1] = (__bf16)fmaxf(v[1] + c.y, 0.f);
        h[2] = (__bf16)fmaxf(v[2] + c.z, 0.f);
        h[3] = (__bf16)fmaxf(v[3] + c.w, 0.f);
        int row = p16 + 16 * mt;
        int col = w * 128 + ot * 16 + quad * 4;
        *(bf16x4v*)(hbuf + row * 512 + (((col >> 3) ^ (row & 7)) << 3) + (col & 7)) = h;
      }
    }
  }
  __syncthreads();

  // ---- phase 2: h2 = relu(h1 @ W2^T + b2) ----
#pragma unroll
  for (int ot = 0; ot < 8; ++ot)
#pragma unroll
    for (int mt = 0; mt < 4; ++mt) { f32x4 z = {0.f, 0.f, 0.f, 0.f}; acc[ot][mt] = z; }

  kloop(w2bf + (size_t)(w * 8) * 8192 + l * 8, hbuf, p16, quad, acc);
  __syncthreads();  // all h1 reads done before overwrite
#pragma unroll
  for (int ot = 0; ot < 8; ++ot) {
    float4 b2 = *(const float4*)(g2b + w * 128 + ot * 16 + quad * 4);
#pragma unroll
    for (int mt = 0; mt < 4; ++mt) {
      f32x4 v = acc[ot][mt];
      bf16x4v h;
      h[0] = (__bf16)fmaxf(v[0] + b2.x, 0.f);
      h[1] = (__bf16)fmaxf(v[1] + b2.y, 0.f);
      h[2] = (__bf16)fmaxf(v[2] + b2.z, 0.f);
      h[3] = (__bf16)fmaxf(v[3] + b2.w, 0.f);
      int row = p16 + 16 * mt;
      int col = w * 128 + ot * 16 + quad * 4;
      *(bf16x4v*)(hbuf + row * 512 + (((col >> 3) ^ (row & 7)) << 3) + (col & 7)) = h;
    }
  }
  __syncthreads();

  // ---- phase 3: h3 = relu(h2 @ W3^T + b3), fused mean-reduce ----
#pragma unroll
  for (int ot = 0; ot < 8; ++ot)
#pragma unroll
    for (int mt = 0; mt < 4; ++mt) { f32x4 z = {0.f, 0.f, 0.f, 0.f}; acc[ot][mt] = z; }

  kloop(w3bf + (size_t)(w * 8) * 8192 + l * 8, hbuf, p16, quad, acc);

#pragma unroll
  for (int ot = 0; ot < 8; ++ot) {
    float4 b3 = *(const float4*)(g3b + w * 128 + ot * 16 + quad * 4);
    float bb[4] = {b3.x, b3.y, b3.z, b3.w};
#pragma unroll
    for (int r = 0; r < 4; ++r) {
      float s = 0.f;
#pragma unroll
      for (int mt = 0; mt < 4; ++mt) s += fmaxf(acc[ot][mt][r] + bb[r], 0.f);
      s += __shfl_xor(s, 1);
      s += __shfl_xor(s, 2);
      s += __shfl_xor(s, 4);
      s += __shfl_xor(s, 8);
      if (p16 == 0)
        atomicAdd(&sent[b * 512 + w * 128 + ot * 16 + quad * 4 + r], s * (1.0f / 4096.0f));
    }
  }
}

// ---------------------------------------------------------------------------
// Head (fused): 64 blocks = 16 b x 4 row-slices of 128, 128 threads (2 waves).
// ---------------------------------------------------------------------------
__global__ __launch_bounds__(128) void k_head(
    const float* __restrict__ d1w, const float* __restrict__ d1b,
    const float* __restrict__ d2w, const float* __restrict__ d2b,
    const float* __restrict__ ws, float* __restrict__ out)
{
  __shared__ float emb[1024];
  const float* sent = (const float*)((const char*)ws + WS_SENT);
  const float* imge = (const float*)((const char*)ws + WS_IMGEMB);
  const int b = blockIdx.x >> 2, sl = blockIdx.x & 3, t = threadIdx.x;
  ((float4*)emb)[t]       = ((const float4*)(sent + b * 512))[t];
  ((float4*)(emb + 512))[t] = ((const float4*)(imge + b * 512))[t];
  __syncthreads();
  const int w2 = t >> 6, l = t & 63;
  float p0 = 0.f, p1 = 0.f;
  for (int rr = 0; rr < 64; ++rr) {
    int row = sl * 128 + w2 * 64 + rr;
    const float* wr = d1w + (size_t)row * 1024 + l * 4;
    float s = 0.f;
#pragma unroll
    for (int c = 0; c < 4; ++c) {
      float4 wv = *(const float4*)(wr + c * 256);
      float4 ev = *(const float4*)(emb + l * 4 + c * 256);
      s += wv.x * ev.x + wv.y * ev.y + wv.z * ev.z + wv.w * ev.w;
    }
#pragma unroll
    for (int m = 32; m >= 1; m >>= 1) s += __shfl_xor(s, m);
    float h = fmaxf(s + d1b[row], 0.f);
    p0 += d2w[row] * h;
    p1 += d2w[512 + row] * h;
  }
  if (l == 0) {
    if (sl == 0 && w2 == 0) { p0 += d2b[0]; p1 += d2b[1]; }
    atomicAdd(&out[b * 2 + 0], p0);
    atomicAdd(&out[b * 2 + 1], p1);
  }
}

// ---------------------------------------------------------------------------
extern "C" void kernel_launch(void* const* d_in, const int* in_sizes, int n_in,
                              void* d_out, int out_size, void* d_ws, size_t ws_size,
                              hipStream_t stream)
{
  const float* input    = (const float*)d_in[0];
  const float* im_input = (const float*)d_in[1];
  const float* g1w = (const float*)d_in[2];
  const float* g1b = (const float*)d_in[3];
  const float* g2w = (const float*)d_in[4];
  const float* g2b = (const float*)d_in[5];
  const float* g3w = (const float*)d_in[6];
  const float* g3b = (const float*)d_in[7];
  const float* imw = (const float*)d_in[8];
  const float* imb = (const float*)d_in[9];
  const float* bng = (const float*)d_in[10];
  const float* bnb = (const float*)d_in[11];
  const float* d1w = (const float*)d_in[12];
  const float* d1b = (const float*)d_in[13];
  const float* d2w = (const float*)d_in[14];
  const float* d2b = (const float*)d_in[15];
  float* out = (float*)d_out;
  float* ws  = (float*)d_ws;

  hipMemsetAsync(d_out, 0, (size_t)out_size * 4, stream);
  k_prep<<<912, 256, 0, stream>>>(input, im_input, g1w, g1b, g2w, g3w, imw, imb, ws);
  k_main<<<1025, 256, 0, stream>>>(input, g2b, g3b, bng, bnb, ws);
  k_head<<<64, 128, 0, stream>>>(d1w, d1b, d2w, d2b, ws, out);
}

// Round 7
// 200.954 us; speedup vs baseline: 1.2997x; 1.0819x over previous
//
#include <hip/hip_runtime.h>

// ---------------------------------------------------------------------------
// Discriminator fused pipeline for MI355X (gfx950) — all-MFMA main kernel,
// M=128 two-tile blocks (halves L2 weight traffic vs one-tile blocks).
//
//   h1[b, i*64+r, o] = relu( A1'[b*64+r, o] + sum_{t<8} W1br[o][t]*x_bi[r*8+t] )
//     A1' = input_flat @ W1a^T + b1 (prep, fp32, MFMA C-frag layout),
//     W1br[o][t] = sum_{u<64} gmlp1_w[o][512+t*64+u]  (prep, bf16, K=32 pad)
//   layers 2,3: transposed MFMA GEMMs D[o][m]; weights A-operand streamed from
//   L2 in pre-swizzled lane-contiguous layout (1 KB/wave/load, R4 prefetch
//   schedule); each A-frag feeds 8 MFMAs (two tiles) for 2x weight reuse.
//   Activations in two XOR-swizzled 64 KB LDS buffers (128 KB total):
//     elem (tile T, r, c) at T*32768 + r*512 + (((c>>3) ^ (r&7))<<3) + (c&7)
//   Weight swizzle: elem (o,k) at (o>>4)*8192 + (k>>5)*512 + (((k>>3)&3)*16+(o&15))*8 + (k&7)
// ---------------------------------------------------------------------------

typedef float f32x4 __attribute__((ext_vector_type(4)));
typedef __bf16 bf16x8v __attribute__((ext_vector_type(8)));
typedef __bf16 bf16x4v __attribute__((ext_vector_type(4)));

// workspace byte offsets
#define WS_A1Q     0u           // 16 x 128 x 64 float4 = 2 MB  (A1+b1, C-frag layout)
#define WS_W1P     2097152u     // 512 x 32 bf16 = 32 KB (W1br zero-padded, A-swizzle)
#define WS_SENT    2129920u     // 16*512 f32 = 32 KB
#define WS_Y       2162688u     // 16*512 f32 = 32 KB (im-linear y)
#define WS_IMGEMB  2195456u     // 16*512 f32 = 32 KB
#define WS_W2BF    2228224u     // 512*512 bf16 = 512 KB (swizzled)
#define WS_W3BF    2752512u     // 512*512 bf16 = 512 KB (swizzled)
// total ~3.11 MB

// ---------------------------------------------------------------------------
// Prep: A1Q GEMM (blocks 0..127), W2/W3 swizzled bf16 convert (128..383),
// W1P + sent-zero (384..399), im-linear y (400..911)
// ---------------------------------------------------------------------------
__global__ __launch_bounds__(256) void k_prep(
    const float* __restrict__ input, const float* __restrict__ im_input,
    const float* __restrict__ g1w, const float* __restrict__ g1b,
    const float* __restrict__ g2w, const float* __restrict__ g3w,
    const float* __restrict__ imw, const float* __restrict__ imb,
    float* __restrict__ ws)
{
  __shared__ float As[16][72];
  __shared__ float Bs[16][72];
  const int blk = blockIdx.x, t = threadIdx.x;
  float4* A1Q = (float4*)ws;
  __bf16* w1p = (__bf16*)((char*)ws + WS_W1P);
  float* sent = (float*)((char*)ws + WS_SENT);
  float* yv   = (float*)((char*)ws + WS_Y);
  __bf16* w2bf = (__bf16*)((char*)ws + WS_W2BF);
  __bf16* w3bf = (__bf16*)((char*)ws + WS_W3BF);

  if (blk < 128) {
    // A1[1024,512] = input_flat @ W1a^T + b1 ; W1a = gmlp1_w[:, :512]
    const int tm = blk >> 3, tn = blk & 7;     // tm = b, tn = o-tile
    const int m0 = tm * 64, o0 = tn * 64;
    const int ty = t >> 4, tx = t & 15;
    const int lrow = t >> 2, lk4 = (t & 3) * 4;
    float acc[4][4] = {};
    for (int kc = 0; kc < 512; kc += 16) {
      float4 av = *(const float4*)(input + (m0 + lrow) * 512 + kc + lk4);
      float4 bw = *(const float4*)(g1w + (size_t)(o0 + lrow) * 1024 + kc + lk4);
      __syncthreads();
      As[lk4 + 0][lrow] = av.x; As[lk4 + 1][lrow] = av.y;
      As[lk4 + 2][lrow] = av.z; As[lk4 + 3][lrow] = av.w;
      Bs[lk4 + 0][lrow] = bw.x; Bs[lk4 + 1][lrow] = bw.y;
      Bs[lk4 + 2][lrow] = bw.z; Bs[lk4 + 3][lrow] = bw.w;
      __syncthreads();
#pragma unroll
      for (int kk = 0; kk < 16; ++kk) {
        float a4[4], b4[4];
        *(float4*)a4 = *(const float4*)&As[kk][4 * ty];
        *(float4*)b4 = *(const float4*)&Bs[kk][4 * tx];
#pragma unroll
        for (int ii = 0; ii < 4; ++ii)
#pragma unroll
          for (int jj = 0; jj < 4; ++jj)
            acc[ii][jj] += a4[ii] * b4[jj];
      }
    }
    // write C-frag layout: A1Q[(b*128 + o4)*64 + m]; o4 = (o0>>2)+tx, m = 4ty+ii
    float4 bias = *(const float4*)(g1b + o0 + 4 * tx);
#pragma unroll
    for (int ii = 0; ii < 4; ++ii) {
      float4 v;
      v.x = acc[ii][0] + bias.x; v.y = acc[ii][1] + bias.y;
      v.z = acc[ii][2] + bias.z; v.w = acc[ii][3] + bias.w;
      A1Q[(tm * 128 + tn * 16 + tx) * 64 + 4 * ty + ii] = v;
    }
  } else if (blk < 384) {
    // convert gmlp2_w / gmlp3_w to bf16 in MFMA A-frag swizzled layout (K=512)
    int idx = ((blk - 128) * 256 + t) * 8;
    const float* src; __bf16* dst; int off;
    if (idx < 262144) { src = g2w; dst = w2bf; off = idx; }
    else              { src = g3w; dst = w3bf; off = idx - 262144; }
    int o = off >> 9, k = off & 511;
    int ks = k >> 5, quad = (k >> 3) & 3;
    int doff = (o >> 4) * 8192 + ks * 512 + (quad * 16 + (o & 15)) * 8;
    float4 v0 = *(const float4*)(src + off);
    float4 v1 = *(const float4*)(src + off + 4);
    bf16x8v h;
    h[0] = (__bf16)v0.x; h[1] = (__bf16)v0.y; h[2] = (__bf16)v0.z; h[3] = (__bf16)v0.w;
    h[4] = (__bf16)v1.x; h[5] = (__bf16)v1.y; h[6] = (__bf16)v1.z; h[7] = (__bf16)v1.w;
    *(bf16x8v*)(dst + doff) = h;
  } else if (blk < 400) {
    // W1P[o][s] = sum_{u<64} gmlp1_w[o][512 + s*64 + u], bf16, A-swizzle, K=32 pad
    int idx = (blk - 384) * 256 + t;      // 0..4095
    int o = idx >> 3, s = idx & 7;
    const float* p = g1w + (size_t)o * 1024 + 512 + s * 64;
    float sum = 0.f;
#pragma unroll
    for (int u = 0; u < 64; u += 4) {
      float4 v = *(const float4*)(p + u);
      sum += v.x + v.y + v.z + v.w;
    }
    int base = (o >> 4) * 512 + (o & 15) * 8 + s;   // quad 0 slot
    w1p[base]       = (__bf16)sum;
    w1p[base + 128] = (__bf16)0.f;                  // quads 1..3 = zero pad
    w1p[base + 256] = (__bf16)0.f;
    w1p[base + 384] = (__bf16)0.f;
    sent[idx] = 0.f; sent[idx + 4096] = 0.f;        // zero accumulator
  } else {
    // y[b][o] = dot(im_input[b], im_w[o]) + im_b[o]; one block per o
    int o = blk - 400;                    // 0..511
    int wv = t >> 6, l = t & 63;
    const float* wrow = imw + (size_t)o * 2048;
    for (int bb = 0; bb < 4; ++bb) {
      int b = wv * 4 + bb;
      const float* xr = im_input + (size_t)b * 2048;
      float s = 0.f;
#pragma unroll
      for (int u = 0; u < 8; ++u) {
        int k = u * 256 + l * 4;
        float4 xv = *(const float4*)(xr + k);
        float4 wx = *(const float4*)(wrow + k);
        s += xv.x * wx.x + xv.y * wx.y + xv.z * wx.z + xv.w * wx.w;
      }
#pragma unroll
      for (int m = 32; m >= 1; m >>= 1) s += __shfl_xor(s, m);
      if (l == 0) yv[b * 512 + o] = s + imb[o];
    }
  }
}

// ---------------------------------------------------------------------------
// Transposed-GEMM K-loop, two-tile (M=128): 4 A-frags x 8 B-frags per ks.
// R4 prefetch schedule: B-reads, A-prefetch, MFMA half, MFMA half, copy.
//   bf[mt]: tile = mt>>2, row = p16 + 16*(mt&3), both tiles' LDS buffers.
// ---------------------------------------------------------------------------
__device__ __forceinline__ void kloop(const __bf16* __restrict__ wl,
                                      const __bf16* __restrict__ hbuf,
                                      int p16, int quad, f32x4 acc[4][8])
{
  const int msk3 = (p16 & 7) << 3;
  int moff[8];
#pragma unroll
  for (int mt = 0; mt < 8; ++mt)
    moff[mt] = (mt >> 2) * 32768 + (p16 + 16 * (mt & 3)) * 512;
  bf16x8v a[4], an[4];
#pragma unroll
  for (int ot = 0; ot < 4; ++ot) a[ot] = *(const bf16x8v*)(wl + ot * 8192);
#pragma unroll 2
  for (int ks = 0; ks < 16; ++ks) {
    const int kcb = (((ks * 4 + quad) << 3) ^ msk3);
    bf16x8v bf[8];
#pragma unroll
    for (int mt = 0; mt < 8; ++mt)
      bf[mt] = *(const bf16x8v*)(hbuf + moff[mt] + kcb);
    if (ks < 15) {
#pragma unroll
      for (int ot = 0; ot < 4; ++ot)
        an[ot] = *(const bf16x8v*)(wl + (ks + 1) * 512 + ot * 8192);
    }
#pragma unroll
    for (int ot = 0; ot < 4; ++ot)
#pragma unroll
      for (int mt = 0; mt < 4; ++mt)
        acc[ot][mt] = __builtin_amdgcn_mfma_f32_16x16x32_bf16(a[ot], bf[mt], acc[ot][mt], 0, 0, 0);
#pragma unroll
    for (int ot = 0; ot < 4; ++ot)
#pragma unroll
      for (int mt = 4; mt < 8; ++mt)
        acc[ot][mt] = __builtin_amdgcn_mfma_f32_16x16x32_bf16(a[ot], bf[mt], acc[ot][mt], 0, 0, 0);
    if (ks < 15) {
#pragma unroll
      for (int ot = 0; ot < 4; ++ot) a[ot] = an[ot];
    }
  }
}

// ---------------------------------------------------------------------------
// Main fused kernel: blocks 0..511 = (b, i-pair) tiles (512 thr, 8 waves,
// two 64x512 LDS h-buffers = 128 KB); block 512 = BatchNorm.
// Wave w covers o in [w*64, w*64+64) via 4 ot; mt 0..3 = tile0, 4..7 = tile1.
// ---------------------------------------------------------------------------
__global__ __launch_bounds__(512, 2) void k_main(
    const float* __restrict__ input,
    const float* __restrict__ g2b, const float* __restrict__ g3b,
    const float* __restrict__ bng, const float* __restrict__ bnb,
    float* __restrict__ ws)
{
  const int blk = blockIdx.x, t = threadIdx.x;
  const float4* A1Q = (const float4*)ws;
  const __bf16* w1p = (const __bf16*)((char*)ws + WS_W1P);
  float* sent = (float*)((char*)ws + WS_SENT);
  float* yv   = (float*)((char*)ws + WS_Y);
  float* imge = (float*)((char*)ws + WS_IMGEMB);
  const __bf16* w2bf = (const __bf16*)((char*)ws + WS_W2BF);
  const __bf16* w3bf = (const __bf16*)((char*)ws + WS_W3BF);

  if (blk == 512) {
    // BatchNorm1d (training-mode batch stats) + ReLU over y[16][512]
    int o = t;
    float vals[16];
    float mu = 0.f;
#pragma unroll
    for (int b = 0; b < 16; ++b) { vals[b] = yv[b * 512 + o]; mu += vals[b]; }
    mu *= (1.f / 16.f);
    float var = 0.f;
#pragma unroll
    for (int b = 0; b < 16; ++b) { float d = vals[b] - mu; var += d * d; }
    var *= (1.f / 16.f);
    float sc = bng[o] * rsqrtf(var + 1e-5f);
    float sh = bnb[o] - mu * sc;
#pragma unroll
    for (int b = 0; b < 16; ++b)
      imge[b * 512 + o] = fmaxf(vals[b] * sc + sh, 0.f);
    return;
  }

  // two swizzled 64x512 bf16 h-buffers = 128 KB (gfx950: 160 KB LDS/CU)
  __shared__ __align__(16) __bf16 hbuf[65536];

  const int b = blk >> 5, ipair = blk & 31;
  const int w = t >> 6, l = t & 63;
  const int quad = l >> 4, p16 = l & 15;

  // x rows for both tiles: lane l holds x[l*8 .. l*8+7]
  float xreg0[8], xreg1[8];
  {
    const float* xr0 = input + (size_t)(b * 64 + ipair * 2) * 512 + l * 8;
    *(float4*)xreg0       = *(const float4*)xr0;
    *(float4*)(xreg0 + 4) = *(const float4*)(xr0 + 4);
    *(float4*)xreg1       = *(const float4*)(xr0 + 512);
    *(float4*)(xreg1 + 4) = *(const float4*)(xr0 + 516);
  }

  f32x4 acc[4][8];

  // ---- phase 1: h1_T = relu(A1' + W1br @ x_T), one K=32 MFMA pass, both tiles ----
  {
    bf16x8v xb[8];
#pragma unroll
    for (int mt = 0; mt < 4; ++mt) {
#pragma unroll
      for (int j = 0; j < 8; ++j) {
        float v0 = __shfl(xreg0[j], p16 + 16 * mt);
        float v1 = __shfl(xreg1[j], p16 + 16 * mt);
        xb[mt][j]     = (quad == 0) ? (__bf16)v0 : (__bf16)0.f;
        xb[mt + 4][j] = (quad == 0) ? (__bf16)v1 : (__bf16)0.f;
      }
    }
#pragma unroll
    for (int ot = 0; ot < 4; ++ot)
#pragma unroll
      for (int mt = 0; mt < 8; ++mt) { f32x4 z = {0.f, 0.f, 0.f, 0.f}; acc[ot][mt] = z; }
#pragma unroll
    for (int ot = 0; ot < 4; ++ot) {
      bf16x8v af = *(const bf16x8v*)(w1p + (w * 4 + ot) * 512 + l * 8);
#pragma unroll
      for (int mt = 0; mt < 8; ++mt)
        acc[ot][mt] = __builtin_amdgcn_mfma_f32_16x16x32_bf16(af, xb[mt], acc[ot][mt], 0, 0, 0);
    }
    // C-add (A1' C-frag layout; same c for both tiles) + relu + swizzled LDS
    const float4* cq = A1Q + ((size_t)b * 128 + w * 16) * 64;
#pragma unroll
    for (int ot = 0; ot < 4; ++ot) {
#pragma unroll
      for (int mtp = 0; mtp < 4; ++mtp) {
        float4 c = cq[(ot * 4 + quad) * 64 + 16 * mtp + p16];
        int row = p16 + 16 * mtp;
        int col = w * 64 + ot * 16 + quad * 4;
        int addr = row * 512 + (((col >> 3) ^ (row & 7)) << 3) + (col & 7);
#pragma unroll
        for (int tau = 0; tau < 2; ++tau) {
          f32x4 v = acc[ot][tau * 4 + mtp];
          bf16x4v h;
          h[0] = (__bf16)fmaxf(v[0] + c.x, 0.f);
          h[1] = (__bf16)fmaxf(v[1] + c.y, 0.f);
          h[2] = (__bf16)fmaxf(v[2] + c.z, 0.f);
          h[3] = (__bf16)fmaxf(v[3] + c.w, 0.f);
          *(bf16x4v*)(hbuf + tau * 32768 + addr) = h;
        }
      }
    }
  }
  __syncthreads();

  // ---- phase 2: h2 = relu(h1 @ W2^T + b2) ----
#pragma unroll
  for (int ot = 0; ot < 4; ++ot)
#pragma unroll
    for (int mt = 0; mt < 8; ++mt) { f32x4 z = {0.f, 0.f, 0.f, 0.f}; acc[ot][mt] = z; }

  kloop(w2bf + (size_t)(w * 4) * 8192 + l * 8, hbuf, p16, quad, acc);
  __syncthreads();  // all h1 reads done before overwrite
#pragma unroll
  for (int ot = 0; ot < 4; ++ot) {
    float4 b2 = *(const float4*)(g2b + w * 64 + ot * 16 + quad * 4);
#pragma unroll
    for (int mt = 0; mt < 8; ++mt) {
      f32x4 v = acc[ot][mt];
      bf16x4v h;
      h[0] = (__bf16)fmaxf(v[0] + b2.x, 0.f);
      h[1] = (__bf16)fmaxf(v[1] + b2.y, 0.f);
      h[2] = (__bf16)fmaxf(v[2] + b2.z, 0.f);
      h[3] = (__bf16)fmaxf(v[3] + b2.w, 0.f);
      int row = p16 + 16 * (mt & 3);
      int col = w * 64 + ot * 16 + quad * 4;
      *(bf16x4v*)(hbuf + (mt >> 2) * 32768 + row * 512 +
                  (((col >> 3) ^ (row & 7)) << 3) + (col & 7)) = h;
    }
  }
  __syncthreads();

  // ---- phase 3: h3 = relu(h2 @ W3^T + b3), fused mean-reduce over both tiles ----
#pragma unroll
  for (int ot = 0; ot < 4; ++ot)
#pragma unroll
    for (int mt = 0; mt < 8; ++mt) { f32x4 z = {0.f, 0.f, 0.f, 0.f}; acc[ot][mt] = z; }

  kloop(w3bf + (size_t)(w * 4) * 8192 + l * 8, hbuf, p16, quad, acc);

#pragma unroll
  for (int ot = 0; ot < 4; ++ot) {
    float4 b3 = *(const float4*)(g3b + w * 64 + ot * 16 + quad * 4);
    float bb[4] = {b3.x, b3.y, b3.z, b3.w};
#pragma unroll
    for (int r = 0; r < 4; ++r) {
      float s = 0.f;
#pragma unroll
      for (int mt = 0; mt < 8; ++mt) s += fmaxf(acc[ot][mt][r] + bb[r], 0.f);
      s += __shfl_xor(s, 1);
      s += __shfl_xor(s, 2);
      s += __shfl_xor(s, 4);
      s += __shfl_xor(s, 8);
      if (p16 == 0)
        atomicAdd(&sent[b * 512 + w * 64 + ot * 16 + quad * 4 + r], s * (1.0f / 4096.0f));
    }
  }
}

// ---------------------------------------------------------------------------
// Head (fused): 64 blocks = 16 b x 4 row-slices of 128, 128 threads (2 waves).
// ---------------------------------------------------------------------------
__global__ __launch_bounds__(128) void k_head(
    const float* __restrict__ d1w, const float* __restrict__ d1b,
    const float* __restrict__ d2w, const float* __restrict__ d2b,
    const float* __restrict__ ws, float* __restrict__ out)
{
  __shared__ float emb[1024];
  const float* sent = (const float*)((const char*)ws + WS_SENT);
  const float* imge = (const float*)((const char*)ws + WS_IMGEMB);
  const int b = blockIdx.x >> 2, sl = blockIdx.x & 3, t = threadIdx.x;
  ((float4*)emb)[t]       = ((const float4*)(sent + b * 512))[t];
  ((float4*)(emb + 512))[t] = ((const float4*)(imge + b * 512))[t];
  __syncthreads();
  const int w2 = t >> 6, l = t & 63;
  float p0 = 0.f, p1 = 0.f;
  for (int rr = 0; rr < 64; ++rr) {
    int row = sl * 128 + w2 * 64 + rr;
    const float* wr = d1w + (size_t)row * 1024 + l * 4;
    float s = 0.f;
#pragma unroll
    for (int c = 0; c < 4; ++c) {
      float4 wv = *(const float4*)(wr + c * 256);
      float4 ev = *(const float4*)(emb + l * 4 + c * 256);
      s += wv.x * ev.x + wv.y * ev.y + wv.z * ev.z + wv.w * ev.w;
    }
#pragma unroll
    for (int m = 32; m >= 1; m >>= 1) s += __shfl_xor(s, m);
    float h = fmaxf(s + d1b[row], 0.f);
    p0 += d2w[row] * h;
    p1 += d2w[512 + row] * h;
  }
  if (l == 0) {
    if (sl == 0 && w2 == 0) { p0 += d2b[0]; p1 += d2b[1]; }
    atomicAdd(&out[b * 2 + 0], p0);
    atomicAdd(&out[b * 2 + 1], p1);
  }
}

// ---------------------------------------------------------------------------
extern "C" void kernel_launch(void* const* d_in, const int* in_sizes, int n_in,
                              void* d_out, int out_size, void* d_ws, size_t ws_size,
                              hipStream_t stream)
{
  const float* input    = (const float*)d_in[0];
  const float* im_input = (const float*)d_in[1];
  const float* g1w = (const float*)d_in[2];
  const float* g1b = (const float*)d_in[3];
  const float* g2w = (const float*)d_in[4];
  const float* g2b = (const float*)d_in[5];
  const float* g3w = (const float*)d_in[6];
  const float* g3b = (const float*)d_in[7];
  const float* imw = (const float*)d_in[8];
  const float* imb = (const float*)d_in[9];
  const float* bng = (const float*)d_in[10];
  const float* bnb = (const float*)d_in[11];
  const float* d1w = (const float*)d_in[12];
  const float* d1b = (const float*)d_in[13];
  const float* d2w = (const float*)d_in[14];
  const float* d2b = (const float*)d_in[15];
  float* out = (float*)d_out;
  float* ws  = (float*)d_ws;

  hipMemsetAsync(d_out, 0, (size_t)out_size * 4, stream);
  k_prep<<<912, 256, 0, stream>>>(input, im_input, g1w, g1b, g2w, g3w, imw, imb, ws);
  k_main<<<513, 512, 0, stream>>>(input, g2b, g3b, bng, bnb, ws);
  k_head<<<64, 128, 0, stream>>>(d1w, d1b, d2w, d2b, ws, out);
}